// Round 13
// baseline (3165.881 us; speedup 1.0000x reference)
//
#include <hip/hip_runtime.h>
#include <cmath>

#define NB   32
#define TE   128
#define TD   32
#define VOC  32000
#define EMB  256
#define HH   512
#define CTXD 1024
#define NR   1536   // GRU gate rows (3*HH)

// ws float offsets. ints 0..2047: barrier regions, 16 groups x 128 ints
// (8 lines x 16 ints each): scan groups 0-7 @0, dec groups 0-7 @1024.
#define OHS  2048                        // harr [2][129][NB][HH] (scan)
#define OEO  (OHS + 2*129*NB*HH)         // enc_out [NB][TE][CTXD]
#define OEP  (OEO + NB*TE*CTXD)          // epre [NB][TE][8]
#define OHD  (OEP + NB*TE*8)             // hdec [TD+1][NB][HH]
#define OVEO (OHD + (TD+1)*NB*HH)        // veo bf16 [NB][NR][TE] (ushort)
#define WSEND (OVEO + NB*NR*TE/2)        // ~48.57MB

typedef __attribute__((ext_vector_type(8))) short bf16x8;
typedef __attribute__((ext_vector_type(4))) float f32x4;

__device__ __forceinline__ float sigf(float x) { return 1.0f / (1.0f + expf(-x)); }
__device__ __forceinline__ float hsum4(float4 v) { return (v.x + v.y) + (v.z + v.w); }

__device__ __forceinline__ void stg1(float* p, float v) {
  __hip_atomic_store(p, v, __ATOMIC_RELAXED, __HIP_MEMORY_SCOPE_AGENT);
}

__device__ __forceinline__ void fma4(float4& a, const float4 w, const float4 u) {
  a.x = fmaf(w.x, u.x, a.x); a.y = fmaf(w.y, u.y, a.y);
  a.z = fmaf(w.z, u.z, a.z); a.w = fmaf(w.w, u.w, a.w);
}

__device__ __forceinline__ unsigned short to_bf16(float f) {
  unsigned int u = __float_as_uint(f);
  u = (u + 0x7FFF + ((u >> 16) & 1)) >> 16;  // round-to-nearest-even
  return (unsigned short)u;
}
__device__ __forceinline__ void cvt_split(float x, short& hi, short& lo) {
  unsigned short h = to_bf16(x);
  float fh = __uint_as_float(((unsigned int)h) << 16);
  hi = (short)h;
  lo = (short)to_bf16(x - fh);
}

// Group-local distributed monotonic barrier (R9 verbatim): 32 participants,
// arrivals over 8 cache lines, wave 0 polls with s_sleep (R10: busy-spin
// REGRESSES — poll flood starves the arrival atomics). All-relaxed
// (agent-acquire = buffer_inv sc1 = L2 nuke, R2). __syncthreads drains vmcnt
// (sc1 stores at L3) before arrival; cross-block data at per-step-fresh addrs.
__device__ __forceinline__ void gbarG(int* bar, int idx, int target) {
  __syncthreads();
  if (threadIdx.x == 0) {
    __hip_atomic_fetch_add(bar + (idx & 7) * 16, 1,
                           __ATOMIC_RELAXED, __HIP_MEMORY_SCOPE_AGENT);
  }
  if (threadIdx.x < 64) {
    const int ln = threadIdx.x;
    int it = 0;
    while (true) {
      int v = (ln < 8)
        ? __hip_atomic_load(bar + ln * 16, __ATOMIC_RELAXED, __HIP_MEMORY_SCOPE_AGENT)
        : 0;
      v += __shfl_xor(v, 1); v += __shfl_xor(v, 2); v += __shfl_xor(v, 4);
      v = __shfl(v, 0);
      if (v >= target) break;
      __builtin_amdgcn_s_sleep(1);
      if (++it > (1 << 20)) break;  // safety bail: garbage beats hang
    }
  }
  __syncthreads();
}
// split-phase halves (same protocol; shadow work may run between them)
__device__ __forceinline__ void gbarArrive(int* bar, int idx) {
  __syncthreads();
  if (threadIdx.x == 0) {
    __hip_atomic_fetch_add(bar + (idx & 7) * 16, 1,
                           __ATOMIC_RELAXED, __HIP_MEMORY_SCOPE_AGENT);
  }
}
__device__ __forceinline__ void gbarWaitS(int* bar, int target) {
  if (threadIdx.x < 64) {
    const int ln = threadIdx.x;
    int it = 0;
    while (true) {
      int v = (ln < 8)
        ? __hip_atomic_load(bar + ln * 16, __ATOMIC_RELAXED, __HIP_MEMORY_SCOPE_AGENT)
        : 0;
      v += __shfl_xor(v, 1); v += __shfl_xor(v, 2); v += __shfl_xor(v, 4);
      v = __shfl(v, 0);
      if (v >= target) break;
      __builtin_amdgcn_s_sleep(1);
      if (++it > (1 << 20)) break;
    }
  }
  __syncthreads();
}

// ---------------- BiLSTM scan: 256 blocks x 512 thr, persistent ----------------
// R12 structure + split-phase: x-dots (token-only, SHADOW) run between arrive
// and wait; on-path = h-dots only ('+=' onto shadow partials).
__global__ void __launch_bounds__(512)
scan_kernel(const int* __restrict__ enc_in, const int* __restrict__ lens,
            const float* __restrict__ emb_src,
            const float* __restrict__ Wih_f, const float* __restrict__ Whh_f,
            const float* __restrict__ bih_f, const float* __restrict__ bhh_f,
            const float* __restrict__ Wih_b, const float* __restrict__ Whh_b,
            const float* __restrict__ bih_b, const float* __restrict__ bhh_b,
            float* __restrict__ ws)
{
  const int tid = threadIdx.x, bid = blockIdx.x;
  const int g = bid & 7, cg = bid >> 3;
  const int dir = g >> 2, bg = g & 3;
  int* bar = (int*)ws + g * 128;
  float* harr = ws + OHS;
  float* eo   = ws + OEO;

  asm volatile("buffer_inv sc1" ::: "memory");  // purge stale clean lines (graph replays)

  __shared__ int   tokL[TE][8];
  __shared__ float lds_p[8][4][68];   // [bb][ks][row 64 + pad]; shadow '=', on-path '+='

  for (int i = tid; i < TE * 8; i += 512) {
    int bb = i & 7, s = i >> 3;
    int b = bg * 8 + bb;
    int t = s;
    if (dir) { int L = lens[b]; t = (s < L) ? (L - 1 - s) : s; }
    tokL[s][bb] = enc_in[b * TE + t];
  }
  if (tid < 128) {
    int bb = tid >> 4, col = tid & 15;
    stg1(&harr[((size_t)(dir * 129) * NB + bg * 8 + bb) * HH + cg * 16 + col], 0.0f);
  }

  const int lane = tid & 63, w = tid >> 6;
  const int ks = w & 3, rh = w >> 2;
  const int rq = lane >> 4, kl = lane & 15;
  const int j0 = cg * 16;
  const float* Wih = dir ? Wih_b : Wih_f;
  const float* Whh = dir ? Whh_b : Whh_f;

  // weights once: rows r = rh*32 + rq*8 + ri; [0] = x chunk c=ks, [1][2] = h chunks
  float4 Wreg[8][3];
  #pragma unroll
  for (int ri = 0; ri < 8; ++ri) {
    int r = rh * 32 + rq * 8 + ri;
    int o = (r >> 4) * HH + j0 + (r & 15);
    Wreg[ri][0] = *((const float4*)Wih + (size_t)o * 64 + ks * 16 + kl);
    Wreg[ri][1] = *((const float4*)Whh + (size_t)o * 128 + (2 * ks) * 16 + kl);
    Wreg[ri][2] = *((const float4*)Whh + (size_t)o * 128 + (2 * ks + 1) * 16 + kl);
  }

  const int b_u = tid >> 4, col_u = tid & 15;
  const int j_u = j0 + col_u;
  const int bglob = bg * 8 + b_u;
  const int Lu = (tid < 128) ? lens[bglob] : 0;
  float bs0 = 0, bs1 = 0, bs2 = 0, bs3 = 0;
  if (tid < 128) {
    const float* bih = dir ? bih_b : bih_f;
    const float* bhh = dir ? bhh_b : bhh_f;
    bs0 = bih[j_u] + bhh[j_u];
    bs1 = bih[HH + j_u] + bhh[HH + j_u];
    bs2 = bih[2 * HH + j_u] + bhh[2 * HH + j_u];
    bs3 = bih[3 * HH + j_u] + bhh[3 * HH + j_u];
  }
  float cst = 0.0f;

  auto SHADOW = [&](int s) {   // x-partials for step s (token-only, pre-wait safe)
    #pragma unroll 2
    for (int bb = 0; bb < 8; ++bb) {
      const int tok = tokL[s][bb];
      float4 ux = *((const float4*)emb_src + (size_t)tok * 64 + ks * 16 + kl);
      float sx[8];
      #pragma unroll
      for (int ri = 0; ri < 8; ++ri) {
        float4 a = {0, 0, 0, 0};
        fma4(a, Wreg[ri][0], ux);
        sx[ri] = hsum4(a);
      }
      #pragma unroll
      for (int ri = 0; ri < 8; ++ri) {
        sx[ri] += __shfl_xor(sx[ri], 1);
        sx[ri] += __shfl_xor(sx[ri], 2);
        sx[ri] += __shfl_xor(sx[ri], 4);
        sx[ri] += __shfl_xor(sx[ri], 8);
      }
      if (kl == 0) {
        int r0 = rh * 32 + rq * 8;
        float4 lo = {sx[0], sx[1], sx[2], sx[3]};
        float4 hi = {sx[4], sx[5], sx[6], sx[7]};
        *(float4*)&lds_p[bb][ks][r0]     = lo;
        *(float4*)&lds_p[bb][ks][r0 + 4] = hi;
      }
    }
  };

  gbarArrive(bar, cg);
  SHADOW(0);
  gbarWaitS(bar, 32);
  int tgt = 64;

  for (int s = 0; s < TE; ++s) {
    // on-path: h-dots (2 chunks) '+='
    {
      const float4* h4 = (const float4*)(harr + ((size_t)(dir * 129 + s) * NB) * HH);
      #pragma unroll 2
      for (int bb = 0; bb < 8; ++bb) {
        const int b = bg * 8 + bb;
        float4 u0 = h4[(size_t)b * 128 + (2 * ks) * 16 + kl];
        float4 u1 = h4[(size_t)b * 128 + (2 * ks + 1) * 16 + kl];
        float sc[8];
        #pragma unroll
        for (int ri = 0; ri < 8; ++ri) {
          float4 a = {0, 0, 0, 0};
          fma4(a, Wreg[ri][1], u0);
          fma4(a, Wreg[ri][2], u1);
          sc[ri] = hsum4(a);
        }
        #pragma unroll
        for (int ri = 0; ri < 8; ++ri) {
          sc[ri] += __shfl_xor(sc[ri], 1);
          sc[ri] += __shfl_xor(sc[ri], 2);
          sc[ri] += __shfl_xor(sc[ri], 4);
          sc[ri] += __shfl_xor(sc[ri], 8);
        }
        if (kl == 0) {
          int r0 = rh * 32 + rq * 8;
          float4 lo = *(float4*)&lds_p[bb][ks][r0];
          float4 hi = *(float4*)&lds_p[bb][ks][r0 + 4];
          lo.x += sc[0]; lo.y += sc[1]; lo.z += sc[2]; lo.w += sc[3];
          hi.x += sc[4]; hi.y += sc[5]; hi.z += sc[6]; hi.w += sc[7];
          *(float4*)&lds_p[bb][ks][r0]     = lo;
          *(float4*)&lds_p[bb][ks][r0 + 4] = hi;
        }
      }
    }
    __syncthreads();

    if (tid < 128) {
      float gi = bs0, gf = bs1, gg = bs2, go = bs3;
      #pragma unroll
      for (int k2 = 0; k2 < 4; ++k2) {
        gi += lds_p[b_u][k2][col_u];
        gf += lds_p[b_u][k2][16 + col_u];
        gg += lds_p[b_u][k2][32 + col_u];
        go += lds_p[b_u][k2][48 + col_u];
      }
      float c = sigf(gf) * cst + sigf(gi) * tanhf(gg);
      cst = c;
      float h = sigf(go) * tanhf(c);
      stg1(&harr[((size_t)(dir * 129 + s + 1) * NB + bglob) * HH + j_u], h);
      float hm = (s < Lu) ? h : 0.0f;
      int pos = dir ? ((s < Lu) ? (Lu - 1 - s) : s) : s;
      eo[((size_t)bglob * TE + pos) * CTXD + dir * HH + j_u] = hm;
    }
    gbarArrive(bar, cg);
    if (s + 1 < TE) SHADOW(s + 1);
    gbarWaitS(bar, tgt); tgt += 32;
  }
}

// ------------- Veo GEMM (R12 verbatim): veo[b][n][t] bf16 ----------
__global__ void __launch_bounds__(256)
veo_kernel(const float* __restrict__ eo, const float* __restrict__ gWih,
           unsigned short* __restrict__ veo)
{
  asm volatile("buffer_inv sc1" ::: "memory");
  __shared__ __align__(16) float As[16][132];
  __shared__ __align__(16) float Bs[16][132];
  const int tid = threadIdx.x;
  const int tx = tid & 15, ty = tid >> 4;
  const int n0 = blockIdx.x * 128, m0 = blockIdx.y * 128;
  float acc[8][8] = {};
  const int lr = tid >> 1;
  const int lk = (tid & 1) * 8;
  const float* arow = eo + (size_t)(m0 + lr) * CTXD;
  const float* brow = gWih + (size_t)(n0 + lr) * (EMB + CTXD) + EMB;

  for (int kc = 0; kc < CTXD; kc += 16) {
    float4 av0 = *(const float4*)&arow[kc + lk];
    float4 av1 = *(const float4*)&arow[kc + lk + 4];
    float4 bv0 = *(const float4*)&brow[kc + lk];
    float4 bv1 = *(const float4*)&brow[kc + lk + 4];
    __syncthreads();
    As[lk + 0][lr] = av0.x; As[lk + 1][lr] = av0.y;
    As[lk + 2][lr] = av0.z; As[lk + 3][lr] = av0.w;
    As[lk + 4][lr] = av1.x; As[lk + 5][lr] = av1.y;
    As[lk + 6][lr] = av1.z; As[lk + 7][lr] = av1.w;
    Bs[lk + 0][lr] = bv0.x; Bs[lk + 1][lr] = bv0.y;
    Bs[lk + 2][lr] = bv0.z; Bs[lk + 3][lr] = bv0.w;
    Bs[lk + 4][lr] = bv1.x; Bs[lk + 5][lr] = bv1.y;
    Bs[lk + 6][lr] = bv1.z; Bs[lk + 7][lr] = bv1.w;
    __syncthreads();
    #pragma unroll
    for (int kk = 0; kk < 16; ++kk) {
      float a8[8], b8[8];
      *(float4*)&a8[0] = *(const float4*)&As[kk][ty * 8];
      *(float4*)&a8[4] = *(const float4*)&As[kk][ty * 8 + 4];
      *(float4*)&b8[0] = *(const float4*)&Bs[kk][tx * 8];
      *(float4*)&b8[4] = *(const float4*)&Bs[kk][tx * 8 + 4];
      #pragma unroll
      for (int i = 0; i < 8; ++i)
        #pragma unroll
        for (int j = 0; j < 8; ++j)
          acc[i][j] = fmaf(a8[i], b8[j], acc[i][j]);
    }
  }
  const int b = m0 >> 7;
  #pragma unroll
  for (int j = 0; j < 8; ++j) {
    int n = n0 + tx * 8 + j;
    unsigned short o8[8];
    #pragma unroll
    for (int i = 0; i < 8; ++i) o8[i] = to_bf16(acc[i][j]);
    *(uint4*)&veo[((size_t)b * NR + n) * TE + ty * 8] = *(uint4*)o8;
  }
}

// ---------------- Decoder (R12 verbatim): ONE sync/step ----------------
__global__ void __launch_bounds__(512)
dec_kernel(const int* __restrict__ dec_in, const int* __restrict__ lens,
           const float* __restrict__ emb_tgt,
           const float* __restrict__ gWih, const float* __restrict__ gWhh,
           const float* __restrict__ gbih, const float* __restrict__ gbhh,
           const float* __restrict__ attn_W, const float* __restrict__ attn_b,
           const float* __restrict__ attn_v,
           float* __restrict__ ws)
{
  const int tid = threadIdx.x, bid = blockIdx.x;
  const int g = bid & 7, cg = bid >> 3;
  const int B4 = g * 4;
  int* bar = (int*)ws + 1024 + g * 128;
  float* eo = ws + OEO;
  float* ep = ws + OEP;
  float* hd = ws + OHD;
  const unsigned short* veoH = (const unsigned short*)(ws + OVEO);

  asm volatile("buffer_inv sc1" ::: "memory");

  __shared__ float hl[4][520];
  __shared__ int   tokD[TD][4];
  __shared__ int   lensh[4];
  __shared__ float av8v[8];
  __shared__ float hpv[4][8];
  __shared__ float elds[4][128];
  __shared__ float wlds[4][128];
  __shared__ float mxs[4], invs[4];
  __shared__ float gvc[4][48];
  __shared__ float lds_pd[2][4][4][52];

  for (int i = tid; i < TD * 4; i += 512)
    tokD[i >> 2][i & 3] = dec_in[(B4 + (i & 3)) * TD + (i >> 2)];
  if (tid < 8) av8v[tid] = attn_v[tid];
  if (tid < 4) lensh[tid] = lens[B4 + tid];

  if (tid < 64) {
    int bb = tid >> 4, col = tid & 15;
    stg1(&hd[(size_t)(B4 + bb) * HH + cg * 16 + col], 0.0f);
  }

  {
    const int idx = cg * 512 + tid;
    if (idx < 4 * TE * 8) {
      int a = idx & 7, t = (idx >> 3) & 127, bb = idx >> 10;
      int b = B4 + bb;
      float acc = attn_b[a];
      const float* er = &eo[((size_t)b * TE + t) * CTXD];
      for (int d = 0; d < CTXD; d += 4) {
        float4 ev = *(const float4*)&er[d];
        acc = fmaf(ev.x, attn_W[(d + 0) * 8 + a], acc);
        acc = fmaf(ev.y, attn_W[(d + 1) * 8 + a], acc);
        acc = fmaf(ev.z, attn_W[(d + 2) * 8 + a], acc);
        acc = fmaf(ev.w, attn_W[(d + 3) * 8 + a], acc);
      }
      stg1(&ep[((size_t)b * TE + t) * 8 + a], acc);
    }
  }

  const int lane = tid & 63, w = tid >> 6;
  const int ks = w & 3, rh = w >> 2;
  const int rq = lane >> 4, kl = lane & 15;
  float4 Wreg[6][3];
  #pragma unroll
  for (int ri = 0; ri < 6; ++ri) {
    int rr = rh * 24 + rq * 6 + ri;
    int row = (rr >> 4) * HH + cg * 16 + (rr & 15);
    #pragma unroll
    for (int p = 0; p < 3; ++p) {
      int c = ks * 3 + p;
      Wreg[ri][p] = (c < 4)
        ? *(const float4*)(gWih + (size_t)row * (EMB + CTXD) + c * 64 + kl * 4)
        : *(const float4*)(gWhh + (size_t)row * HH + (c - 4) * 64 + kl * 4);
    }
  }

  const int ub = tid >> 4, ucol = tid & 15;
  const int uj = cg * 16 + ucol;
  float bRc = 0, bZc = 0, bNi = 0, bNh = 0;
  if (tid < 64) {
    bRc = gbih[uj] + gbhh[uj];
    bZc = gbih[HH + uj] + gbhh[HH + uj];
    bNi = gbih[2 * HH + uj];
    bNh = gbhh[2 * HH + uj];
  }

  int tgt = 32;
  gbarG(bar, cg, tgt); tgt += 32;

  for (int s = 0; s < TD; ++s) {
    {
      int bb = tid >> 7, c4 = (tid & 127) * 4;
      *(float4*)&hl[bb][c4] =
        *(const float4*)&hd[((size_t)s * NB + B4 + bb) * HH + c4];
    }
    __syncthreads();
    {
      const int bb = w >> 1;
      const float4* h4 = (const float4*)&hl[bb][0];
      float4 ha = h4[lane * 2], hb = h4[lane * 2 + 1];
      #pragma unroll
      for (int i = 0; i < 4; ++i) {
        const int a = (w & 1) * 4 + i;
        const float* wa = attn_W + (size_t)(CTXD + lane * 8) * 8 + a;
        float acc = 0.0f;
        acc = fmaf(ha.x, wa[0],  acc); acc = fmaf(ha.y, wa[8],  acc);
        acc = fmaf(ha.z, wa[16], acc); acc = fmaf(ha.w, wa[24], acc);
        acc = fmaf(hb.x, wa[32], acc); acc = fmaf(hb.y, wa[40], acc);
        acc = fmaf(hb.z, wa[48], acc); acc = fmaf(hb.w, wa[56], acc);
        acc += __shfl_xor(acc, 1);  acc += __shfl_xor(acc, 2);
        acc += __shfl_xor(acc, 4);  acc += __shfl_xor(acc, 8);
        acc += __shfl_xor(acc, 16); acc += __shfl_xor(acc, 32);
        if (lane == 0) hpv[bb][a] = acc;
      }
    }
    __syncthreads();
    {
      const int bb = tid >> 7, t = tid & 127;
      const int b = B4 + bb;
      float evv = -1e9f;
      if (t < lensh[bb]) {
        const float* e8 = &ep[((size_t)b * TE + t) * 8];
        float4 ea = *(const float4*)e8, eb2 = *(const float4*)(e8 + 4);
        evv  = tanhf(ea.x + hpv[bb][0]) * av8v[0];
        evv += tanhf(ea.y + hpv[bb][1]) * av8v[1];
        evv += tanhf(ea.z + hpv[bb][2]) * av8v[2];
        evv += tanhf(ea.w + hpv[bb][3]) * av8v[3];
        evv += tanhf(eb2.x + hpv[bb][4]) * av8v[4];
        evv += tanhf(eb2.y + hpv[bb][5]) * av8v[5];
        evv += tanhf(eb2.z + hpv[bb][6]) * av8v[6];
        evv += tanhf(eb2.w + hpv[bb][7]) * av8v[7];
      }
      elds[bb][t] = evv;
    }
    __syncthreads();
    if (tid < 256) {
      const int bb = tid >> 6, i = tid & 63;
      float m = fmaxf(elds[bb][i], elds[bb][i + 64]);
      m = fmaxf(m, __shfl_xor(m, 1));  m = fmaxf(m, __shfl_xor(m, 2));
      m = fmaxf(m, __shfl_xor(m, 4));  m = fmaxf(m, __shfl_xor(m, 8));
      m = fmaxf(m, __shfl_xor(m, 16)); m = fmaxf(m, __shfl_xor(m, 32));
      if (i == 0) mxs[bb] = m;
    }
    __syncthreads();
    {
      const int bb = tid >> 7, t = tid & 127;
      wlds[bb][t] = expf(elds[bb][t] - mxs[bb]);
    }
    __syncthreads();
    if (tid < 256) {
      const int bb = tid >> 6, i = tid & 63;
      float sm = wlds[bb][i] + wlds[bb][i + 64];
      sm += __shfl_xor(sm, 1);  sm += __shfl_xor(sm, 2);
      sm += __shfl_xor(sm, 4);  sm += __shfl_xor(sm, 8);
      sm += __shfl_xor(sm, 16); sm += __shfl_xor(sm, 32);
      if (i == 0) invs[bb] = 1.0f / sm;
    }
    {
      #pragma unroll
      for (int bb = 0; bb < 4; ++bb) {
        const float4* xr = (const float4*)(emb_tgt + (size_t)tokD[s][bb] * EMB);
        float4 u[3];
        #pragma unroll
        for (int p = 0; p < 3; ++p) {
          int c = ks * 3 + p;
          u[p] = (c < 4) ? xr[c * 16 + kl]
                         : *(const float4*)&hl[bb][(c - 4) * 64 + kl * 4];
        }
        float sI[6], sH[6];
        #pragma unroll
        for (int ri = 0; ri < 6; ++ri) {
          float4 aI = {0,0,0,0}, aH = {0,0,0,0};
          #pragma unroll
          for (int p = 0; p < 3; ++p) {
            int c = ks * 3 + p;
            if (c < 4) fma4(aI, Wreg[ri][p], u[p]);
            else       fma4(aH, Wreg[ri][p], u[p]);
          }
          sI[ri] = hsum4(aI); sH[ri] = hsum4(aH);
        }
        #pragma unroll
        for (int ri = 0; ri < 6; ++ri) {
          sI[ri] += __shfl_xor(sI[ri], 1); sH[ri] += __shfl_xor(sH[ri], 1);
          sI[ri] += __shfl_xor(sI[ri], 2); sH[ri] += __shfl_xor(sH[ri], 2);
          sI[ri] += __shfl_xor(sI[ri], 4); sH[ri] += __shfl_xor(sH[ri], 4);
          sI[ri] += __shfl_xor(sI[ri], 8); sH[ri] += __shfl_xor(sH[ri], 8);
        }
        if (kl == 0) {
          int r0 = rh * 24 + rq * 6;
          #pragma unroll
          for (int ri = 0; ri < 6; ++ri) {
            lds_pd[0][bb][ks][r0 + ri] = sI[ri];
            lds_pd[1][bb][ks][r0 + ri] = sH[ri];
          }
        }
      }
    }
    __syncthreads();
    if (tid < 384) {
      const int bb = tid / 96, idx = tid % 96;
      const int rr = idx >> 1, th = idx & 1;
      const int n = (rr >> 4) * HH + cg * 16 + (rr & 15);
      const unsigned short* vp = veoH + ((size_t)(B4 + bb) * NR + n) * TE + th * 64;
      const float* wl = &wlds[bb][th * 64];
      float acc = 0.0f;
      #pragma unroll
      for (int q = 0; q < 8; ++q) {
        uint4 pk = *(const uint4*)&vp[q * 8];
        unsigned int uu[4] = {pk.x, pk.y, pk.z, pk.w};
        #pragma unroll
        for (int h2 = 0; h2 < 4; ++h2) {
          acc = fmaf(wl[q * 8 + h2 * 2 + 0],
                     __uint_as_float((uu[h2] & 0xFFFFu) << 16), acc);
          acc = fmaf(wl[q * 8 + h2 * 2 + 1],
                     __uint_as_float((uu[h2] >> 16) << 16), acc);
        }
      }
      acc += __shfl_xor(acc, 1);
      if (th == 0) gvc[bb][rr] = acc * invs[bb];
    }
    __syncthreads();
    if (tid < 64) {
      float giR = gvc[ub][ucol], ghR = 0;
      float giZ = gvc[ub][16 + ucol], ghZ = 0;
      float giN = gvc[ub][32 + ucol], ghN = 0;
      #pragma unroll
      for (int k2 = 0; k2 < 4; ++k2) {
        giR += lds_pd[0][ub][k2][ucol];      ghR += lds_pd[1][ub][k2][ucol];
        giZ += lds_pd[0][ub][k2][16 + ucol]; ghZ += lds_pd[1][ub][k2][16 + ucol];
        giN += lds_pd[0][ub][k2][32 + ucol]; ghN += lds_pd[1][ub][k2][32 + ucol];
      }
      float r = sigf(giR + ghR + bRc);
      float z = sigf(giZ + ghZ + bZc);
      float n = tanhf(giN + bNi + r * (ghN + bNh));
      float hnew = (1.0f - z) * n + z * hl[ub][uj];
      stg1(&hd[((size_t)(s + 1) * NB + B4 + ub) * HH + uj], hnew);
    }
    gbarG(bar, cg, tgt); tgt += 32;
  }
}

// -------- Classifier: bf16 MFMA with 2-term error compensation --------
// out = relu(hd @ W^T + b). Split x = hi+lo (bf16); acc = hi*hi + hi*lo + lo*hi
// -> ~fp32 accuracy. Frags load directly from global (A: h rows; B: W rows),
// layouts per documented mapping (D: col=lane&15, row=(lane>>4)*4+reg).
__global__ void __launch_bounds__(256)
clf_kernel(const float* __restrict__ hd, const float* __restrict__ W,
           const float* __restrict__ bias, float* __restrict__ out)
{
  asm volatile("buffer_inv sc1" ::: "memory");
  const int tid = threadIdx.x;
  const int wv = tid >> 6, l = tid & 63;
  const int lr = l & 15, lk = (l >> 4) * 8;
  const int n0 = blockIdx.x * 64 + wv * 16;   // wave's 16 output cols
  const int m0 = blockIdx.y * 64;
  const float* arow[4];
  #pragma unroll
  for (int ms = 0; ms < 4; ++ms) {
    int r = m0 + ms * 16 + lr;                // r = b*TD + t
    arow[ms] = hd + ((size_t)((r & 31) + 1) * NB + (r >> 5)) * HH + lk;
  }
  const float* brow = W + (size_t)(n0 + lr) * HH + lk;
  f32x4 acc[4] = {};

  for (int kc = 0; kc < HH; kc += 32) {
    bf16x8 bh, bl;
    {
      float4 b0 = *(const float4*)&brow[kc];
      float4 b1 = *(const float4*)&brow[kc + 4];
      float bf[8] = {b0.x, b0.y, b0.z, b0.w, b1.x, b1.y, b1.z, b1.w};
      #pragma unroll
      for (int i = 0; i < 8; ++i) { short h, lo2; cvt_split(bf[i], h, lo2); bh[i] = h; bl[i] = lo2; }
    }
    #pragma unroll
    for (int ms = 0; ms < 4; ++ms) {
      float4 a0 = *(const float4*)&arow[ms][kc];
      float4 a1 = *(const float4*)&arow[ms][kc + 4];
      float af[8] = {a0.x, a0.y, a0.z, a0.w, a1.x, a1.y, a1.z, a1.w};
      bf16x8 ah, al;
      #pragma unroll
      for (int i = 0; i < 8; ++i) { short h, lo2; cvt_split(af[i], h, lo2); ah[i] = h; al[i] = lo2; }
      acc[ms] = __builtin_amdgcn_mfma_f32_16x16x32_bf16(ah, bh, acc[ms], 0, 0, 0);
      acc[ms] = __builtin_amdgcn_mfma_f32_16x16x32_bf16(ah, bl, acc[ms], 0, 0, 0);
      acc[ms] = __builtin_amdgcn_mfma_f32_16x16x32_bf16(al, bh, acc[ms], 0, 0, 0);
    }
  }
  const float bn = bias[n0 + lr];
  #pragma unroll
  for (int ms = 0; ms < 4; ++ms) {
    #pragma unroll
    for (int r = 0; r < 4; ++r) {
      int m = m0 + ms * 16 + (l >> 4) * 4 + r;
      out[(size_t)m * VOC + n0 + lr] = fmaxf(acc[ms][r] + bn, 0.0f);
    }
  }
}

extern "C" void kernel_launch(void* const* d_in, const int* in_sizes, int n_in,
                              void* d_out, int out_size, void* d_ws, size_t ws_size,
                              hipStream_t stream)
{
  if (ws_size < (size_t)WSEND * 4) return;  // visible-failure guard

  const int* enc_in  = (const int*)d_in[0];
  const int* enc_len = (const int*)d_in[1];
  const int* dec_in  = (const int*)d_in[2];
  const float* emb_src = (const float*)d_in[4];
  const float* emb_tgt = (const float*)d_in[5];
  const float* Wih_f = (const float*)d_in[6];
  const float* Whh_f = (const float*)d_in[7];
  const float* bih_f = (const float*)d_in[8];
  const float* bhh_f = (const float*)d_in[9];
  const float* Wih_b = (const float*)d_in[10];
  const float* Whh_b = (const float*)d_in[11];
  const float* bih_b = (const float*)d_in[12];
  const float* bhh_b = (const float*)d_in[13];
  const float* gWih  = (const float*)d_in[14];
  const float* gWhh  = (const float*)d_in[15];
  const float* gbih  = (const float*)d_in[16];
  const float* gbhh  = (const float*)d_in[17];
  const float* attn_W = (const float*)d_in[18];
  const float* attn_b = (const float*)d_in[19];
  const float* attn_v = (const float*)d_in[20];
  const float* clf_W = (const float*)d_in[21];
  const float* clf_b = (const float*)d_in[22];
  float* ws  = (float*)d_ws;
  float* out = (float*)d_out;

  hipMemsetAsync(d_ws, 0, 8192, stream);  // barrier lines (16 groups)
  scan_kernel<<<256, 512, 0, stream>>>(enc_in, enc_len, emb_src,
      Wih_f, Whh_f, bih_f, bhh_f, Wih_b, Whh_b, bih_b, bhh_b, ws);
  veo_kernel<<<dim3(NR / 128, (NB * TE) / 128), 256, 0, stream>>>(
      ws + OEO, gWih, (unsigned short*)(ws + OVEO));
  dec_kernel<<<256, 512, 0, stream>>>(dec_in, enc_len, emb_tgt,
      gWih, gWhh, gbih, gbhh, attn_W, attn_b, attn_v, ws);
  dim3 cg(VOC / 64, (NB * TD) / 64);
  clf_kernel<<<cg, 256, 0, stream>>>(ws + OHD, clf_W, clf_b, out);
}

// Round 14
// 2157.127 us; speedup vs baseline: 1.4676x; 1.4676x over previous
//
#include <hip/hip_runtime.h>
#include <cmath>

#define NB   32
#define TE   128
#define TD   32
#define VOC  32000
#define EMB  256
#define HH   512
#define CTXD 1024
#define NR   1536   // GRU gate rows (3*HH)

// ws float offsets. ints 0..2047: barrier regions, 16 groups x 128 ints
// (8 lines x 16 ints each): scan groups 0-7 @0, dec groups 0-7 @1024.
#define OHS  2048                        // harr [2][129][NB][HH] (scan) -> reused as Abh/Abl after dec
#define OEO  (OHS + 2*129*NB*HH)         // enc_out [NB][TE][CTXD]
#define OEP  (OEO + NB*TE*CTXD)          // epre [NB][TE][8]
#define OHD  (OEP + NB*TE*8)             // hdec [TD+1][NB][HH]
#define OVEO (OHD + (TD+1)*NB*HH)        // veo bf16 [NB][NR][TE] (ushort)
#define WSEND (OVEO + NB*NR*TE/2)        // ~48.57MB

typedef __attribute__((ext_vector_type(8))) short bf16x8;
typedef __attribute__((ext_vector_type(4))) float f32x4;

__device__ __forceinline__ float sigf(float x) { return 1.0f / (1.0f + expf(-x)); }
__device__ __forceinline__ float hsum4(float4 v) { return (v.x + v.y) + (v.z + v.w); }

__device__ __forceinline__ void stg1(float* p, float v) {
  __hip_atomic_store(p, v, __ATOMIC_RELAXED, __HIP_MEMORY_SCOPE_AGENT);
}

__device__ __forceinline__ void fma4(float4& a, const float4 w, const float4 u) {
  a.x = fmaf(w.x, u.x, a.x); a.y = fmaf(w.y, u.y, a.y);
  a.z = fmaf(w.z, u.z, a.z); a.w = fmaf(w.w, u.w, a.w);
}

__device__ __forceinline__ unsigned short to_bf16(float f) {
  unsigned int u = __float_as_uint(f);
  u = (u + 0x7FFF + ((u >> 16) & 1)) >> 16;  // round-to-nearest-even
  return (unsigned short)u;
}

// Group-local distributed monotonic barrier (R9/R12 verbatim): 32 participants,
// arrivals over 8 cache lines, wave 0 polls with s_sleep. All-relaxed
// (agent-acquire = buffer_inv sc1 = L2 nuke, R2). __syncthreads drains vmcnt
// (sc1 stores at L3) before arrival; cross-block data at per-step-fresh addrs.
// NOTE: split-phase/shadow variants REGRESS (R10, R13) — do not reintroduce.
__device__ __forceinline__ void gbarG(int* bar, int idx, int target) {
  __syncthreads();
  if (threadIdx.x == 0) {
    __hip_atomic_fetch_add(bar + (idx & 7) * 16, 1,
                           __ATOMIC_RELAXED, __HIP_MEMORY_SCOPE_AGENT);
  }
  if (threadIdx.x < 64) {
    const int ln = threadIdx.x;
    int it = 0;
    while (true) {
      int v = (ln < 8)
        ? __hip_atomic_load(bar + ln * 16, __ATOMIC_RELAXED, __HIP_MEMORY_SCOPE_AGENT)
        : 0;
      v += __shfl_xor(v, 1); v += __shfl_xor(v, 2); v += __shfl_xor(v, 4);
      v = __shfl(v, 0);
      if (v >= target) break;
      __builtin_amdgcn_s_sleep(1);
      if (++it > (1 << 20)) break;  // safety bail: garbage beats hang
    }
  }
  __syncthreads();
}

// ---------------- BiLSTM scan: 256 blocks x 512 thr (R12 verbatim) ----------------
__global__ void __launch_bounds__(512)
scan_kernel(const int* __restrict__ enc_in, const int* __restrict__ lens,
            const float* __restrict__ emb_src,
            const float* __restrict__ Wih_f, const float* __restrict__ Whh_f,
            const float* __restrict__ bih_f, const float* __restrict__ bhh_f,
            const float* __restrict__ Wih_b, const float* __restrict__ Whh_b,
            const float* __restrict__ bih_b, const float* __restrict__ bhh_b,
            float* __restrict__ ws)
{
  const int tid = threadIdx.x, bid = blockIdx.x;
  const int g = bid & 7, cg = bid >> 3;
  const int dir = g >> 2, bg = g & 3;
  int* bar = (int*)ws + g * 128;
  float* harr = ws + OHS;
  float* eo   = ws + OEO;

  asm volatile("buffer_inv sc1" ::: "memory");  // purge stale clean lines (graph replays)

  __shared__ int   tokL[TE][8];
  __shared__ float lds_p[8][4][68];

  for (int i = tid; i < TE * 8; i += 512) {
    int bb = i & 7, s = i >> 3;
    int b = bg * 8 + bb;
    int t = s;
    if (dir) { int L = lens[b]; t = (s < L) ? (L - 1 - s) : s; }
    tokL[s][bb] = enc_in[b * TE + t];
  }
  if (tid < 128) {
    int bb = tid >> 4, col = tid & 15;
    stg1(&harr[((size_t)(dir * 129) * NB + bg * 8 + bb) * HH + cg * 16 + col], 0.0f);
  }

  const int lane = tid & 63, w = tid >> 6;
  const int ks = w & 3, rh = w >> 2;
  const int rq = lane >> 4, kl = lane & 15;
  const int j0 = cg * 16;
  const float* Wih = dir ? Wih_b : Wih_f;
  const float* Whh = dir ? Whh_b : Whh_f;

  float4 Wreg[8][3];
  #pragma unroll
  for (int ri = 0; ri < 8; ++ri) {
    int r = rh * 32 + rq * 8 + ri;
    int o = (r >> 4) * HH + j0 + (r & 15);
    #pragma unroll
    for (int p = 0; p < 3; ++p) {
      int kf = (ks * 3 + p) * 16 + kl;
      Wreg[ri][p] = (kf < 64)
        ? *((const float4*)Wih + (size_t)o * 64 + kf)
        : *((const float4*)Whh + (size_t)o * 128 + (kf - 64));
    }
  }

  const int b_u = tid >> 4, col_u = tid & 15;
  const int j_u = j0 + col_u;
  const int bglob = bg * 8 + b_u;
  const int Lu = (tid < 128) ? lens[bglob] : 0;
  float bs0 = 0, bs1 = 0, bs2 = 0, bs3 = 0;
  if (tid < 128) {
    const float* bih = dir ? bih_b : bih_f;
    const float* bhh = dir ? bhh_b : bhh_f;
    bs0 = bih[j_u] + bhh[j_u];
    bs1 = bih[HH + j_u] + bhh[HH + j_u];
    bs2 = bih[2 * HH + j_u] + bhh[2 * HH + j_u];
    bs3 = bih[3 * HH + j_u] + bhh[3 * HH + j_u];
  }
  float cst = 0.0f;

  int tgt = 32;
  gbarG(bar, cg, tgt); tgt += 32;

  for (int s = 0; s < TE; ++s) {
    const float4* h4 = (const float4*)(harr + ((size_t)(dir * 129 + s) * NB) * HH);
    #pragma unroll 2
    for (int bb = 0; bb < 8; ++bb) {
      const int b = bg * 8 + bb;
      const int tok = tokL[s][bb];
      const float4* x4 = (const float4*)emb_src + (size_t)tok * 64;
      float4 u[3];
      #pragma unroll
      for (int p = 0; p < 3; ++p) {
        int c = ks * 3 + p;
        u[p] = (c < 4) ? x4[c * 16 + kl]
                       : h4[(size_t)b * 128 + (c - 4) * 16 + kl];
      }
      float sc[8];
      #pragma unroll
      for (int ri = 0; ri < 8; ++ri) {
        float4 a = {0, 0, 0, 0};
        fma4(a, Wreg[ri][0], u[0]);
        fma4(a, Wreg[ri][1], u[1]);
        fma4(a, Wreg[ri][2], u[2]);
        sc[ri] = hsum4(a);
      }
      #pragma unroll
      for (int ri = 0; ri < 8; ++ri) {
        sc[ri] += __shfl_xor(sc[ri], 1);
        sc[ri] += __shfl_xor(sc[ri], 2);
        sc[ri] += __shfl_xor(sc[ri], 4);
        sc[ri] += __shfl_xor(sc[ri], 8);
      }
      if (kl == 0) {
        int r0 = rh * 32 + rq * 8;
        float4 lo = {sc[0], sc[1], sc[2], sc[3]};
        float4 hi = {sc[4], sc[5], sc[6], sc[7]};
        *(float4*)&lds_p[bb][ks][r0]     = lo;
        *(float4*)&lds_p[bb][ks][r0 + 4] = hi;
      }
    }
    __syncthreads();

    if (tid < 128) {
      float gi = bs0, gf = bs1, gg = bs2, go = bs3;
      #pragma unroll
      for (int k2 = 0; k2 < 4; ++k2) {
        gi += lds_p[b_u][k2][col_u];
        gf += lds_p[b_u][k2][16 + col_u];
        gg += lds_p[b_u][k2][32 + col_u];
        go += lds_p[b_u][k2][48 + col_u];
      }
      float c = sigf(gf) * cst + sigf(gi) * tanhf(gg);
      cst = c;
      float h = sigf(go) * tanhf(c);
      stg1(&harr[((size_t)(dir * 129 + s + 1) * NB + bglob) * HH + j_u], h);
      float hm = (s < Lu) ? h : 0.0f;
      int pos = dir ? ((s < Lu) ? (Lu - 1 - s) : s) : s;
      eo[((size_t)bglob * TE + pos) * CTXD + dir * HH + j_u] = hm;
    }
    gbarG(bar, cg, tgt); tgt += 32;
  }
}

// ------------- Veo GEMM (R12 verbatim): veo[b][n][t] bf16 ----------
__global__ void __launch_bounds__(256)
veo_kernel(const float* __restrict__ eo, const float* __restrict__ gWih,
           unsigned short* __restrict__ veo)
{
  asm volatile("buffer_inv sc1" ::: "memory");
  __shared__ __align__(16) float As[16][132];
  __shared__ __align__(16) float Bs[16][132];
  const int tid = threadIdx.x;
  const int tx = tid & 15, ty = tid >> 4;
  const int n0 = blockIdx.x * 128, m0 = blockIdx.y * 128;
  float acc[8][8] = {};
  const int lr = tid >> 1;
  const int lk = (tid & 1) * 8;
  const float* arow = eo + (size_t)(m0 + lr) * CTXD;
  const float* brow = gWih + (size_t)(n0 + lr) * (EMB + CTXD) + EMB;

  for (int kc = 0; kc < CTXD; kc += 16) {
    float4 av0 = *(const float4*)&arow[kc + lk];
    float4 av1 = *(const float4*)&arow[kc + lk + 4];
    float4 bv0 = *(const float4*)&brow[kc + lk];
    float4 bv1 = *(const float4*)&brow[kc + lk + 4];
    __syncthreads();
    As[lk + 0][lr] = av0.x; As[lk + 1][lr] = av0.y;
    As[lk + 2][lr] = av0.z; As[lk + 3][lr] = av0.w;
    As[lk + 4][lr] = av1.x; As[lk + 5][lr] = av1.y;
    As[lk + 6][lr] = av1.z; As[lk + 7][lr] = av1.w;
    Bs[lk + 0][lr] = bv0.x; Bs[lk + 1][lr] = bv0.y;
    Bs[lk + 2][lr] = bv0.z; Bs[lk + 3][lr] = bv0.w;
    Bs[lk + 4][lr] = bv1.x; Bs[lk + 5][lr] = bv1.y;
    Bs[lk + 6][lr] = bv1.z; Bs[lk + 7][lr] = bv1.w;
    __syncthreads();
    #pragma unroll
    for (int kk = 0; kk < 16; ++kk) {
      float a8[8], b8[8];
      *(float4*)&a8[0] = *(const float4*)&As[kk][ty * 8];
      *(float4*)&a8[4] = *(const float4*)&As[kk][ty * 8 + 4];
      *(float4*)&b8[0] = *(const float4*)&Bs[kk][tx * 8];
      *(float4*)&b8[4] = *(const float4*)&Bs[kk][tx * 8 + 4];
      #pragma unroll
      for (int i = 0; i < 8; ++i)
        #pragma unroll
        for (int j = 0; j < 8; ++j)
          acc[i][j] = fmaf(a8[i], b8[j], acc[i][j]);
    }
  }
  const int b = m0 >> 7;
  #pragma unroll
  for (int j = 0; j < 8; ++j) {
    int n = n0 + tx * 8 + j;
    unsigned short o8[8];
    #pragma unroll
    for (int i = 0; i < 8; ++i) o8[i] = to_bf16(acc[i][j]);
    *(uint4*)&veo[((size_t)b * NR + n) * TE + ty * 8] = *(uint4*)o8;
  }
}

// ---------------- Decoder (R12 verbatim): ONE sync/step ----------------
__global__ void __launch_bounds__(512)
dec_kernel(const int* __restrict__ dec_in, const int* __restrict__ lens,
           const float* __restrict__ emb_tgt,
           const float* __restrict__ gWih, const float* __restrict__ gWhh,
           const float* __restrict__ gbih, const float* __restrict__ gbhh,
           const float* __restrict__ attn_W, const float* __restrict__ attn_b,
           const float* __restrict__ attn_v,
           float* __restrict__ ws)
{
  const int tid = threadIdx.x, bid = blockIdx.x;
  const int g = bid & 7, cg = bid >> 3;
  const int B4 = g * 4;
  int* bar = (int*)ws + 1024 + g * 128;
  float* eo = ws + OEO;
  float* ep = ws + OEP;
  float* hd = ws + OHD;
  const unsigned short* veoH = (const unsigned short*)(ws + OVEO);

  asm volatile("buffer_inv sc1" ::: "memory");

  __shared__ float hl[4][520];
  __shared__ int   tokD[TD][4];
  __shared__ int   lensh[4];
  __shared__ float av8v[8];
  __shared__ float hpv[4][8];
  __shared__ float elds[4][128];
  __shared__ float wlds[4][128];
  __shared__ float mxs[4], invs[4];
  __shared__ float gvc[4][48];
  __shared__ float lds_pd[2][4][4][52];

  for (int i = tid; i < TD * 4; i += 512)
    tokD[i >> 2][i & 3] = dec_in[(B4 + (i & 3)) * TD + (i >> 2)];
  if (tid < 8) av8v[tid] = attn_v[tid];
  if (tid < 4) lensh[tid] = lens[B4 + tid];

  if (tid < 64) {
    int bb = tid >> 4, col = tid & 15;
    stg1(&hd[(size_t)(B4 + bb) * HH + cg * 16 + col], 0.0f);
  }

  {
    const int idx = cg * 512 + tid;
    if (idx < 4 * TE * 8) {
      int a = idx & 7, t = (idx >> 3) & 127, bb = idx >> 10;
      int b = B4 + bb;
      float acc = attn_b[a];
      const float* er = &eo[((size_t)b * TE + t) * CTXD];
      for (int d = 0; d < CTXD; d += 4) {
        float4 ev = *(const float4*)&er[d];
        acc = fmaf(ev.x, attn_W[(d + 0) * 8 + a], acc);
        acc = fmaf(ev.y, attn_W[(d + 1) * 8 + a], acc);
        acc = fmaf(ev.z, attn_W[(d + 2) * 8 + a], acc);
        acc = fmaf(ev.w, attn_W[(d + 3) * 8 + a], acc);
      }
      stg1(&ep[((size_t)b * TE + t) * 8 + a], acc);
    }
  }

  const int lane = tid & 63, w = tid >> 6;
  const int ks = w & 3, rh = w >> 2;
  const int rq = lane >> 4, kl = lane & 15;
  float4 Wreg[6][3];
  #pragma unroll
  for (int ri = 0; ri < 6; ++ri) {
    int rr = rh * 24 + rq * 6 + ri;
    int row = (rr >> 4) * HH + cg * 16 + (rr & 15);
    #pragma unroll
    for (int p = 0; p < 3; ++p) {
      int c = ks * 3 + p;
      Wreg[ri][p] = (c < 4)
        ? *(const float4*)(gWih + (size_t)row * (EMB + CTXD) + c * 64 + kl * 4)
        : *(const float4*)(gWhh + (size_t)row * HH + (c - 4) * 64 + kl * 4);
    }
  }

  const int ub = tid >> 4, ucol = tid & 15;
  const int uj = cg * 16 + ucol;
  float bRc = 0, bZc = 0, bNi = 0, bNh = 0;
  if (tid < 64) {
    bRc = gbih[uj] + gbhh[uj];
    bZc = gbih[HH + uj] + gbhh[HH + uj];
    bNi = gbih[2 * HH + uj];
    bNh = gbhh[2 * HH + uj];
  }

  int tgt = 32;
  gbarG(bar, cg, tgt); tgt += 32;

  for (int s = 0; s < TD; ++s) {
    {
      int bb = tid >> 7, c4 = (tid & 127) * 4;
      *(float4*)&hl[bb][c4] =
        *(const float4*)&hd[((size_t)s * NB + B4 + bb) * HH + c4];
    }
    __syncthreads();
    {
      const int bb = w >> 1;
      const float4* h4 = (const float4*)&hl[bb][0];
      float4 ha = h4[lane * 2], hb = h4[lane * 2 + 1];
      #pragma unroll
      for (int i = 0; i < 4; ++i) {
        const int a = (w & 1) * 4 + i;
        const float* wa = attn_W + (size_t)(CTXD + lane * 8) * 8 + a;
        float acc = 0.0f;
        acc = fmaf(ha.x, wa[0],  acc); acc = fmaf(ha.y, wa[8],  acc);
        acc = fmaf(ha.z, wa[16], acc); acc = fmaf(ha.w, wa[24], acc);
        acc = fmaf(hb.x, wa[32], acc); acc = fmaf(hb.y, wa[40], acc);
        acc = fmaf(hb.z, wa[48], acc); acc = fmaf(hb.w, wa[56], acc);
        acc += __shfl_xor(acc, 1);  acc += __shfl_xor(acc, 2);
        acc += __shfl_xor(acc, 4);  acc += __shfl_xor(acc, 8);
        acc += __shfl_xor(acc, 16); acc += __shfl_xor(acc, 32);
        if (lane == 0) hpv[bb][a] = acc;
      }
    }
    __syncthreads();
    {
      const int bb = tid >> 7, t = tid & 127;
      const int b = B4 + bb;
      float evv = -1e9f;
      if (t < lensh[bb]) {
        const float* e8 = &ep[((size_t)b * TE + t) * 8];
        float4 ea = *(const float4*)e8, eb2 = *(const float4*)(e8 + 4);
        evv  = tanhf(ea.x + hpv[bb][0]) * av8v[0];
        evv += tanhf(ea.y + hpv[bb][1]) * av8v[1];
        evv += tanhf(ea.z + hpv[bb][2]) * av8v[2];
        evv += tanhf(ea.w + hpv[bb][3]) * av8v[3];
        evv += tanhf(eb2.x + hpv[bb][4]) * av8v[4];
        evv += tanhf(eb2.y + hpv[bb][5]) * av8v[5];
        evv += tanhf(eb2.z + hpv[bb][6]) * av8v[6];
        evv += tanhf(eb2.w + hpv[bb][7]) * av8v[7];
      }
      elds[bb][t] = evv;
    }
    __syncthreads();
    if (tid < 256) {
      const int bb = tid >> 6, i = tid & 63;
      float m = fmaxf(elds[bb][i], elds[bb][i + 64]);
      m = fmaxf(m, __shfl_xor(m, 1));  m = fmaxf(m, __shfl_xor(m, 2));
      m = fmaxf(m, __shfl_xor(m, 4));  m = fmaxf(m, __shfl_xor(m, 8));
      m = fmaxf(m, __shfl_xor(m, 16)); m = fmaxf(m, __shfl_xor(m, 32));
      if (i == 0) mxs[bb] = m;
    }
    __syncthreads();
    {
      const int bb = tid >> 7, t = tid & 127;
      wlds[bb][t] = expf(elds[bb][t] - mxs[bb]);
    }
    __syncthreads();
    if (tid < 256) {
      const int bb = tid >> 6, i = tid & 63;
      float sm = wlds[bb][i] + wlds[bb][i + 64];
      sm += __shfl_xor(sm, 1);  sm += __shfl_xor(sm, 2);
      sm += __shfl_xor(sm, 4);  sm += __shfl_xor(sm, 8);
      sm += __shfl_xor(sm, 16); sm += __shfl_xor(sm, 32);
      if (i == 0) invs[bb] = 1.0f / sm;
    }
    {
      #pragma unroll
      for (int bb = 0; bb < 4; ++bb) {
        const float4* xr = (const float4*)(emb_tgt + (size_t)tokD[s][bb] * EMB);
        float4 u[3];
        #pragma unroll
        for (int p = 0; p < 3; ++p) {
          int c = ks * 3 + p;
          u[p] = (c < 4) ? xr[c * 16 + kl]
                         : *(const float4*)&hl[bb][(c - 4) * 64 + kl * 4];
        }
        float sI[6], sH[6];
        #pragma unroll
        for (int ri = 0; ri < 6; ++ri) {
          float4 aI = {0,0,0,0}, aH = {0,0,0,0};
          #pragma unroll
          for (int p = 0; p < 3; ++p) {
            int c = ks * 3 + p;
            if (c < 4) fma4(aI, Wreg[ri][p], u[p]);
            else       fma4(aH, Wreg[ri][p], u[p]);
          }
          sI[ri] = hsum4(aI); sH[ri] = hsum4(aH);
        }
        #pragma unroll
        for (int ri = 0; ri < 6; ++ri) {
          sI[ri] += __shfl_xor(sI[ri], 1); sH[ri] += __shfl_xor(sH[ri], 1);
          sI[ri] += __shfl_xor(sI[ri], 2); sH[ri] += __shfl_xor(sH[ri], 2);
          sI[ri] += __shfl_xor(sI[ri], 4); sH[ri] += __shfl_xor(sH[ri], 4);
          sI[ri] += __shfl_xor(sI[ri], 8); sH[ri] += __shfl_xor(sH[ri], 8);
        }
        if (kl == 0) {
          int r0 = rh * 24 + rq * 6;
          #pragma unroll
          for (int ri = 0; ri < 6; ++ri) {
            lds_pd[0][bb][ks][r0 + ri] = sI[ri];
            lds_pd[1][bb][ks][r0 + ri] = sH[ri];
          }
        }
      }
    }
    __syncthreads();
    if (tid < 384) {
      const int bb = tid / 96, idx = tid % 96;
      const int rr = idx >> 1, th = idx & 1;
      const int n = (rr >> 4) * HH + cg * 16 + (rr & 15);
      const unsigned short* vp = veoH + ((size_t)(B4 + bb) * NR + n) * TE + th * 64;
      const float* wl = &wlds[bb][th * 64];
      float acc = 0.0f;
      #pragma unroll
      for (int q = 0; q < 8; ++q) {
        uint4 pk = *(const uint4*)&vp[q * 8];
        unsigned int uu[4] = {pk.x, pk.y, pk.z, pk.w};
        #pragma unroll
        for (int h2 = 0; h2 < 4; ++h2) {
          acc = fmaf(wl[q * 8 + h2 * 2 + 0],
                     __uint_as_float((uu[h2] & 0xFFFFu) << 16), acc);
          acc = fmaf(wl[q * 8 + h2 * 2 + 1],
                     __uint_as_float((uu[h2] >> 16) << 16), acc);
        }
      }
      acc += __shfl_xor(acc, 1);
      if (th == 0) gvc[bb][rr] = acc * invs[bb];
    }
    __syncthreads();
    if (tid < 64) {
      float giR = gvc[ub][ucol], ghR = 0;
      float giZ = gvc[ub][16 + ucol], ghZ = 0;
      float giN = gvc[ub][32 + ucol], ghN = 0;
      #pragma unroll
      for (int k2 = 0; k2 < 4; ++k2) {
        giR += lds_pd[0][ub][k2][ucol];      ghR += lds_pd[1][ub][k2][ucol];
        giZ += lds_pd[0][ub][k2][16 + ucol]; ghZ += lds_pd[1][ub][k2][16 + ucol];
        giN += lds_pd[0][ub][k2][32 + ucol]; ghN += lds_pd[1][ub][k2][32 + ucol];
      }
      float r = sigf(giR + ghR + bRc);
      float z = sigf(giZ + ghZ + bZc);
      float n = tanhf(giN + bNi + r * (ghN + bNh));
      float hnew = (1.0f - z) * n + z * hl[ub][uj];
      stg1(&hd[((size_t)(s + 1) * NB + B4 + ub) * HH + uj], hnew);
    }
    gbarG(bar, cg, tgt); tgt += 32;
  }
}

// ------- conv: split hdec into exact bf16 hi+lo, output-row (m) order -------
// Abh/Abl [1024][512] shorts, stored in the dead harr region.
__global__ void __launch_bounds__(256)
conv_kernel(const float* __restrict__ hd,
            unsigned short* __restrict__ Abh, unsigned short* __restrict__ Abl)
{
  asm volatile("buffer_inv sc1" ::: "memory");
  const int idx = blockIdx.x * 256 + threadIdx.x;   // 0..65535
  const int m = idx >> 6;
  const int k8 = (idx & 63) * 8;
  const float* src = hd + ((size_t)((m & 31) + 1) * NB + (m >> 5)) * HH + k8;
  float4 a0 = *(const float4*)src;
  float4 a1 = *(const float4*)(src + 4);
  float f[8] = {a0.x, a0.y, a0.z, a0.w, a1.x, a1.y, a1.z, a1.w};
  unsigned short hi[8], lo[8];
  #pragma unroll
  for (int i = 0; i < 8; ++i) {
    unsigned short h = to_bf16(f[i]);
    float fh = __uint_as_float(((unsigned int)h) << 16);
    hi[i] = h;
    lo[i] = to_bf16(f[i] - fh);
  }
  *(uint4*)&Abh[(size_t)m * HH + k8] = *(uint4*)hi;
  *(uint4*)&Abl[(size_t)m * HH + k8] = *(uint4*)lo;
}

// -------- Classifier: bf16 MFMA, LDS-staged, 2-term compensation --------
// out = relu(A @ W^T + b), A = Ah+Al (exact bf16 split, precomputed);
// acc = Ah*Wh + Al*Wh (W-lo term skipped: bounded err ~1e-4 << 1.9e-3 thr).
// Block tile 256m x 128n, 4 waves (wave = 32 n-cols), 16 kc of 32.
__global__ void __launch_bounds__(256)
clf_kernel(const unsigned short* __restrict__ Abh, const unsigned short* __restrict__ Abl,
           const float* __restrict__ W, const float* __restrict__ bias,
           float* __restrict__ out)
{
  asm volatile("buffer_inv sc1" ::: "memory");
  __shared__ __align__(16) unsigned short Ah[256][40];   // pad 40 -> 80B stride
  __shared__ __align__(16) unsigned short Al[256][40];
  __shared__ __align__(16) unsigned short Wh[128][40];
  const int tid = threadIdx.x;
  const int wv = tid >> 6, l = tid & 63;
  const int lr = l & 15, lkq = l >> 4;
  const int n0 = blockIdx.x * 128, m0 = blockIdx.y * 256;
  f32x4 acc[2][16] = {};

  for (int kc = 0; kc < HH; kc += 32) {
    __syncthreads();
    {
      // A stage: thread t -> row t (64B hi + 64B lo)
      const unsigned short* sh = Abh + (size_t)(m0 + tid) * HH + kc;
      const unsigned short* sl = Abl + (size_t)(m0 + tid) * HH + kc;
      uint4 h0 = *(const uint4*)(sh);      uint4 h1 = *(const uint4*)(sh + 8);
      uint4 h2 = *(const uint4*)(sh + 16); uint4 h3 = *(const uint4*)(sh + 24);
      uint4 l0 = *(const uint4*)(sl);      uint4 l1 = *(const uint4*)(sl + 8);
      uint4 l2 = *(const uint4*)(sl + 16); uint4 l3 = *(const uint4*)(sl + 24);
      *(uint4*)&Ah[tid][0]  = h0; *(uint4*)&Ah[tid][8]  = h1;
      *(uint4*)&Ah[tid][16] = h2; *(uint4*)&Ah[tid][24] = h3;
      *(uint4*)&Al[tid][0]  = l0; *(uint4*)&Al[tid][8]  = l1;
      *(uint4*)&Al[tid][16] = l2; *(uint4*)&Al[tid][24] = l3;
      // W stage: thread t -> (row t>>1, half t&1): 16 fp32 -> bf16 hi
      const int wr = tid >> 1, hf = tid & 1;
      const float* wsrc = W + (size_t)(n0 + wr) * HH + kc + hf * 16;
      unsigned int o[8];
      #pragma unroll
      for (int i = 0; i < 16; i += 4) {
        float4 v = *(const float4*)&wsrc[i];
        o[(i >> 1) + 0] = (unsigned int)to_bf16(v.x) | ((unsigned int)to_bf16(v.y) << 16);
        o[(i >> 1) + 1] = (unsigned int)to_bf16(v.z) | ((unsigned int)to_bf16(v.w) << 16);
      }
      *(uint4*)&Wh[wr][hf * 16]     = *(uint4*)&o[0];
      *(uint4*)&Wh[wr][hf * 16 + 8] = *(uint4*)&o[4];
    }
    __syncthreads();
    bf16x8 bfr[2];
    bfr[0] = *(const bf16x8*)&Wh[wv * 32 + lr][lkq * 8];
    bfr[1] = *(const bf16x8*)&Wh[wv * 32 + 16 + lr][lkq * 8];
    #pragma unroll
    for (int mf = 0; mf < 16; ++mf) {
      bf16x8 ah = *(const bf16x8*)&Ah[mf * 16 + lr][lkq * 8];
      bf16x8 al = *(const bf16x8*)&Al[mf * 16 + lr][lkq * 8];
      #pragma unroll
      for (int nf = 0; nf < 2; ++nf) {
        acc[nf][mf] = __builtin_amdgcn_mfma_f32_16x16x32_bf16(ah, bfr[nf], acc[nf][mf], 0, 0, 0);
        acc[nf][mf] = __builtin_amdgcn_mfma_f32_16x16x32_bf16(al, bfr[nf], acc[nf][mf], 0, 0, 0);
      }
    }
  }
  #pragma unroll
  for (int nf = 0; nf < 2; ++nf) {
    const int n = n0 + wv * 32 + nf * 16 + lr;
    const float bn = bias[n];
    #pragma unroll
    for (int mf = 0; mf < 16; ++mf) {
      #pragma unroll
      for (int r = 0; r < 4; ++r) {
        int m = m0 + mf * 16 + lkq * 4 + r;
        out[(size_t)m * VOC + n] = fmaxf(acc[nf][mf][r] + bn, 0.0f);
      }
    }
  }
}

extern "C" void kernel_launch(void* const* d_in, const int* in_sizes, int n_in,
                              void* d_out, int out_size, void* d_ws, size_t ws_size,
                              hipStream_t stream)
{
  if (ws_size < (size_t)WSEND * 4) return;  // visible-failure guard

  const int* enc_in  = (const int*)d_in[0];
  const int* enc_len = (const int*)d_in[1];
  const int* dec_in  = (const int*)d_in[2];
  const float* emb_src = (const float*)d_in[4];
  const float* emb_tgt = (const float*)d_in[5];
  const float* Wih_f = (const float*)d_in[6];
  const float* Whh_f = (const float*)d_in[7];
  const float* bih_f = (const float*)d_in[8];
  const float* bhh_f = (const float*)d_in[9];
  const float* Wih_b = (const float*)d_in[10];
  const float* Whh_b = (const float*)d_in[11];
  const float* bih_b = (const float*)d_in[12];
  const float* bhh_b = (const float*)d_in[13];
  const float* gWih  = (const float*)d_in[14];
  const float* gWhh  = (const float*)d_in[15];
  const float* gbih  = (const float*)d_in[16];
  const float* gbhh  = (const float*)d_in[17];
  const float* attn_W = (const float*)d_in[18];
  const float* attn_b = (const float*)d_in[19];
  const float* attn_v = (const float*)d_in[20];
  const float* clf_W = (const float*)d_in[21];
  const float* clf_b = (const float*)d_in[22];
  float* ws  = (float*)d_ws;
  float* out = (float*)d_out;

  unsigned short* Abh = (unsigned short*)(ws + OHS);          // dead harr region
  unsigned short* Abl = Abh + (size_t)NB * TD * HH;

  hipMemsetAsync(d_ws, 0, 8192, stream);  // barrier lines (16 groups)
  scan_kernel<<<256, 512, 0, stream>>>(enc_in, enc_len, emb_src,
      Wih_f, Whh_f, bih_f, bhh_f, Wih_b, Whh_b, bih_b, bhh_b, ws);
  veo_kernel<<<dim3(NR / 128, (NB * TE) / 128), 256, 0, stream>>>(
      ws + OEO, gWih, (unsigned short*)(ws + OVEO));
  dec_kernel<<<256, 512, 0, stream>>>(dec_in, enc_len, emb_tgt,
      gWih, gWhh, gbih, gbhh, attn_W, attn_b, attn_v, ws);
  conv_kernel<<<256, 256, 0, stream>>>(ws + OHD, Abh, Abl);
  dim3 cg(VOC / 128, (NB * TD) / 256);
  clf_kernel<<<cg, 256, 0, stream>>>(Abh, Abl, clf_W, clf_b, out);
}

// Round 15
// 2009.282 us; speedup vs baseline: 1.5756x; 1.0736x over previous
//
#include <hip/hip_runtime.h>
#include <cmath>

#define NB   32
#define TE   128
#define TD   32
#define VOC  32000
#define EMB  256
#define HH   512
#define CTXD 1024
#define NR   1536   // GRU gate rows (3*HH)

// ws int layout: scan flags 8 groups x 32 producers x 16 ints = ints 0..4095;
// dec barrier regions: ints 4096 + g*128 (8 groups). floats from OHS.
#define OHS  8192                        // harr [2][129][NB][HH] (scan) -> Abh/Abl after dec
#define OEO  (OHS + 2*129*NB*HH)         // enc_out [NB][TE][CTXD]
#define OEP  (OEO + NB*TE*CTXD)          // epre [NB][TE][8]
#define OHD  (OEP + NB*TE*8)             // hdec [TD+1][NB][HH]
#define OVEO (OHD + (TD+1)*NB*HH)        // veo bf16 [NB][NR][TE] (ushort)
#define WSEND (OVEO + NB*NR*TE/2)        // ~48.59MB

typedef __attribute__((ext_vector_type(8))) short bf16x8;
typedef __attribute__((ext_vector_type(4))) float f32x4;

__device__ __forceinline__ float sigf(float x) { return 1.0f / (1.0f + expf(-x)); }
__device__ __forceinline__ float hsum4(float4 v) { return (v.x + v.y) + (v.z + v.w); }

__device__ __forceinline__ void stg1(float* p, float v) {
  __hip_atomic_store(p, v, __ATOMIC_RELAXED, __HIP_MEMORY_SCOPE_AGENT);
}

__device__ __forceinline__ void fma4(float4& a, const float4 w, const float4 u) {
  a.x = fmaf(w.x, u.x, a.x); a.y = fmaf(w.y, u.y, a.y);
  a.z = fmaf(w.z, u.z, a.z); a.w = fmaf(w.w, u.w, a.w);
}

__device__ __forceinline__ unsigned short to_bf16(float f) {
  unsigned int u = __float_as_uint(f);
  u = (u + 0x7FFF + ((u >> 16) & 1)) >> 16;  // round-to-nearest-even
  return (unsigned short)u;
}

// Group-local distributed monotonic barrier (dec only; R9/R12 verbatim).
// All-relaxed (agent-acquire = buffer_inv sc1 = L2 nuke, R2). s_sleep poll
// (busy-spin regresses, R10). __syncthreads drains vmcnt before arrival.
__device__ __forceinline__ void gbarG(int* bar, int idx, int target) {
  __syncthreads();
  if (threadIdx.x == 0) {
    __hip_atomic_fetch_add(bar + (idx & 7) * 16, 1,
                           __ATOMIC_RELAXED, __HIP_MEMORY_SCOPE_AGENT);
  }
  if (threadIdx.x < 64) {
    const int ln = threadIdx.x;
    int it = 0;
    while (true) {
      int v = (ln < 8)
        ? __hip_atomic_load(bar + ln * 16, __ATOMIC_RELAXED, __HIP_MEMORY_SCOPE_AGENT)
        : 0;
      v += __shfl_xor(v, 1); v += __shfl_xor(v, 2); v += __shfl_xor(v, 4);
      v = __shfl(v, 0);
      if (v >= target) break;
      __builtin_amdgcn_s_sleep(1);
      if (++it > (1 << 20)) break;  // safety bail: garbage beats hang
    }
  }
  __syncthreads();
}

// ---------------- BiLSTM scan: 256 blocks x 512 thr, persistent ----------------
// R12 compute structure, but sync = PER-PRODUCER FLAGS: flag[g][cg] = number of
// h-steps published by col-block cg (monotonic, agent-scope). Each wave waits
// only on the producers of ITS h-chunks (ks=0 waves: none - natural x-shadow,
// no dot-loop restructure). Publication semantics identical to the old barrier:
// __syncthreads (vmcnt drained, sc1 h-stores at L3) then flag store.
__global__ void __launch_bounds__(512)
scan_kernel(const int* __restrict__ enc_in, const int* __restrict__ lens,
            const float* __restrict__ emb_src,
            const float* __restrict__ Wih_f, const float* __restrict__ Whh_f,
            const float* __restrict__ bih_f, const float* __restrict__ bhh_f,
            const float* __restrict__ Wih_b, const float* __restrict__ Whh_b,
            const float* __restrict__ bih_b, const float* __restrict__ bhh_b,
            float* __restrict__ ws)
{
  const int tid = threadIdx.x, bid = blockIdx.x;
  const int g = bid & 7, cg = bid >> 3;
  const int dir = g >> 2, bg = g & 3;
  int* flg = (int*)ws + g * 512;          // 32 producers x 16 ints
  float* harr = ws + OHS;
  float* eo   = ws + OEO;

  asm volatile("buffer_inv sc1" ::: "memory");  // purge stale clean lines (graph replays)

  __shared__ int   tokL[TE][8];
  __shared__ float lds_p[8][4][68];

  for (int i = tid; i < TE * 8; i += 512) {
    int bb = i & 7, s = i >> 3;
    int b = bg * 8 + bb;
    int t = s;
    if (dir) { int L = lens[b]; t = (s < L) ? (L - 1 - s) : s; }
    tokL[s][bb] = enc_in[b * TE + t];
  }
  if (tid < 128) {
    int bb = tid >> 4, col = tid & 15;
    stg1(&harr[((size_t)(dir * 129) * NB + bg * 8 + bb) * HH + cg * 16 + col], 0.0f);
  }

  const int lane = tid & 63, w = tid >> 6;
  const int ks = w & 3, rh = w >> 2;
  const int rq = lane >> 4, kl = lane & 15;
  const int j0 = cg * 16;
  const float* Wih = dir ? Wih_b : Wih_f;
  const float* Whh = dir ? Whh_b : Whh_f;

  float4 Wreg[8][3];
  #pragma unroll
  for (int ri = 0; ri < 8; ++ri) {
    int r = rh * 32 + rq * 8 + ri;
    int o = (r >> 4) * HH + j0 + (r & 15);
    #pragma unroll
    for (int p = 0; p < 3; ++p) {
      int kf = (ks * 3 + p) * 16 + kl;
      Wreg[ri][p] = (kf < 64)
        ? *((const float4*)Wih + (size_t)o * 64 + kf)
        : *((const float4*)Whh + (size_t)o * 128 + (kf - 64));
    }
  }

  const int b_u = tid >> 4, col_u = tid & 15;
  const int j_u = j0 + col_u;
  const int bglob = bg * 8 + b_u;
  const int Lu = (tid < 128) ? lens[bglob] : 0;
  float bs0 = 0, bs1 = 0, bs2 = 0, bs3 = 0;
  if (tid < 128) {
    const float* bih = dir ? bih_b : bih_f;
    const float* bhh = dir ? bhh_b : bhh_f;
    bs0 = bih[j_u] + bhh[j_u];
    bs1 = bih[HH + j_u] + bhh[HH + j_u];
    bs2 = bih[2 * HH + j_u] + bhh[2 * HH + j_u];
    bs3 = bih[3 * HH + j_u] + bhh[3 * HH + j_u];
  }
  float cst = 0.0f;

  // producer set of this wave's h-chunks (hc = ks*3+p-4):
  // ks=0: none (pure x); ks=1: cg 0..7; ks=2: cg 8..19; ks=3: cg 20..31
  const int pbase = (ks == 1) ? 0 : (ks == 2) ? 8 : 20;
  const int pnum  = (ks == 1) ? 8 : 12;

  // publish h0 (flag = 1)
  __syncthreads();
  if (tid == 0)
    __hip_atomic_store(flg + cg * 16, 1, __ATOMIC_RELAXED, __HIP_MEMORY_SCOPE_AGENT);

  for (int s = 0; s < TE; ++s) {
    // per-wave wait: only the producers this wave consumes (h_s => flag >= s+1)
    if (ks != 0) {
      int it = 0;
      while (true) {
        int v = (lane < pnum)
          ? __hip_atomic_load(flg + (pbase + lane) * 16,
                              __ATOMIC_RELAXED, __HIP_MEMORY_SCOPE_AGENT)
          : 0x7fffffff;
        v = min(v, __shfl_xor(v, 1));  v = min(v, __shfl_xor(v, 2));
        v = min(v, __shfl_xor(v, 4));  v = min(v, __shfl_xor(v, 8));
        v = min(v, __shfl_xor(v, 16)); v = min(v, __shfl_xor(v, 32));
        if (v >= s + 1) break;
        __builtin_amdgcn_s_sleep(1);
        if (++it > (1 << 20)) break;  // safety bail: garbage beats hang
      }
    }

    const float4* h4 = (const float4*)(harr + ((size_t)(dir * 129 + s) * NB) * HH);
    #pragma unroll 2
    for (int bb = 0; bb < 8; ++bb) {
      const int b = bg * 8 + bb;
      const int tok = tokL[s][bb];
      const float4* x4 = (const float4*)emb_src + (size_t)tok * 64;
      float4 u[3];
      #pragma unroll
      for (int p = 0; p < 3; ++p) {
        int c = ks * 3 + p;
        u[p] = (c < 4) ? x4[c * 16 + kl]
                       : h4[(size_t)b * 128 + (c - 4) * 16 + kl];
      }
      float sc[8];
      #pragma unroll
      for (int ri = 0; ri < 8; ++ri) {
        float4 a = {0, 0, 0, 0};
        fma4(a, Wreg[ri][0], u[0]);
        fma4(a, Wreg[ri][1], u[1]);
        fma4(a, Wreg[ri][2], u[2]);
        sc[ri] = hsum4(a);
      }
      #pragma unroll
      for (int ri = 0; ri < 8; ++ri) {
        sc[ri] += __shfl_xor(sc[ri], 1);
        sc[ri] += __shfl_xor(sc[ri], 2);
        sc[ri] += __shfl_xor(sc[ri], 4);
        sc[ri] += __shfl_xor(sc[ri], 8);
      }
      if (kl == 0) {
        int r0 = rh * 32 + rq * 8;
        float4 lo = {sc[0], sc[1], sc[2], sc[3]};
        float4 hi = {sc[4], sc[5], sc[6], sc[7]};
        *(float4*)&lds_p[bb][ks][r0]     = lo;
        *(float4*)&lds_p[bb][ks][r0 + 4] = hi;
      }
    }
    __syncthreads();

    if (tid < 128) {
      float gi = bs0, gf = bs1, gg = bs2, go = bs3;
      #pragma unroll
      for (int k2 = 0; k2 < 4; ++k2) {
        gi += lds_p[b_u][k2][col_u];
        gf += lds_p[b_u][k2][16 + col_u];
        gg += lds_p[b_u][k2][32 + col_u];
        go += lds_p[b_u][k2][48 + col_u];
      }
      float c = sigf(gf) * cst + sigf(gi) * tanhf(gg);
      cst = c;
      float h = sigf(go) * tanhf(c);
      stg1(&harr[((size_t)(dir * 129 + s + 1) * NB + bglob) * HH + j_u], h);
      float hm = (s < Lu) ? h : 0.0f;
      int pos = dir ? ((s < Lu) ? (Lu - 1 - s) : s) : s;
      eo[((size_t)bglob * TE + pos) * CTXD + dir * HH + j_u] = hm;
    }
    __syncthreads();   // drain updaters' sc1 h-stores (vmcnt 0 per wave)
    if (tid == 0)
      __hip_atomic_store(flg + cg * 16, s + 2,
                         __ATOMIC_RELAXED, __HIP_MEMORY_SCOPE_AGENT);
  }
}

// ------------- Veo GEMM (R12 verbatim): veo[b][n][t] bf16 ----------
__global__ void __launch_bounds__(256)
veo_kernel(const float* __restrict__ eo, const float* __restrict__ gWih,
           unsigned short* __restrict__ veo)
{
  asm volatile("buffer_inv sc1" ::: "memory");
  __shared__ __align__(16) float As[16][132];
  __shared__ __align__(16) float Bs[16][132];
  const int tid = threadIdx.x;
  const int tx = tid & 15, ty = tid >> 4;
  const int n0 = blockIdx.x * 128, m0 = blockIdx.y * 128;
  float acc[8][8] = {};
  const int lr = tid >> 1;
  const int lk = (tid & 1) * 8;
  const float* arow = eo + (size_t)(m0 + lr) * CTXD;
  const float* brow = gWih + (size_t)(n0 + lr) * (EMB + CTXD) + EMB;

  for (int kc = 0; kc < CTXD; kc += 16) {
    float4 av0 = *(const float4*)&arow[kc + lk];
    float4 av1 = *(const float4*)&arow[kc + lk + 4];
    float4 bv0 = *(const float4*)&brow[kc + lk];
    float4 bv1 = *(const float4*)&brow[kc + lk + 4];
    __syncthreads();
    As[lk + 0][lr] = av0.x; As[lk + 1][lr] = av0.y;
    As[lk + 2][lr] = av0.z; As[lk + 3][lr] = av0.w;
    As[lk + 4][lr] = av1.x; As[lk + 5][lr] = av1.y;
    As[lk + 6][lr] = av1.z; As[lk + 7][lr] = av1.w;
    Bs[lk + 0][lr] = bv0.x; Bs[lk + 1][lr] = bv0.y;
    Bs[lk + 2][lr] = bv0.z; Bs[lk + 3][lr] = bv0.w;
    Bs[lk + 4][lr] = bv1.x; Bs[lk + 5][lr] = bv1.y;
    Bs[lk + 6][lr] = bv1.z; Bs[lk + 7][lr] = bv1.w;
    __syncthreads();
    #pragma unroll
    for (int kk = 0; kk < 16; ++kk) {
      float a8[8], b8[8];
      *(float4*)&a8[0] = *(const float4*)&As[kk][ty * 8];
      *(float4*)&a8[4] = *(const float4*)&As[kk][ty * 8 + 4];
      *(float4*)&b8[0] = *(const float4*)&Bs[kk][tx * 8];
      *(float4*)&b8[4] = *(const float4*)&Bs[kk][tx * 8 + 4];
      #pragma unroll
      for (int i = 0; i < 8; ++i)
        #pragma unroll
        for (int j = 0; j < 8; ++j)
          acc[i][j] = fmaf(a8[i], b8[j], acc[i][j]);
    }
  }
  const int b = m0 >> 7;
  #pragma unroll
  for (int j = 0; j < 8; ++j) {
    int n = n0 + tx * 8 + j;
    unsigned short o8[8];
    #pragma unroll
    for (int i = 0; i < 8; ++i) o8[i] = to_bf16(acc[i][j]);
    *(uint4*)&veo[((size_t)b * NR + n) * TE + ty * 8] = *(uint4*)o8;
  }
}

// ---------------- Decoder (R12 verbatim): ONE sync/step ----------------
__global__ void __launch_bounds__(512)
dec_kernel(const int* __restrict__ dec_in, const int* __restrict__ lens,
           const float* __restrict__ emb_tgt,
           const float* __restrict__ gWih, const float* __restrict__ gWhh,
           const float* __restrict__ gbih, const float* __restrict__ gbhh,
           const float* __restrict__ attn_W, const float* __restrict__ attn_b,
           const float* __restrict__ attn_v,
           float* __restrict__ ws)
{
  const int tid = threadIdx.x, bid = blockIdx.x;
  const int g = bid & 7, cg = bid >> 3;
  const int B4 = g * 4;
  int* bar = (int*)ws + 4096 + g * 128;
  float* eo = ws + OEO;
  float* ep = ws + OEP;
  float* hd = ws + OHD;
  const unsigned short* veoH = (const unsigned short*)(ws + OVEO);

  asm volatile("buffer_inv sc1" ::: "memory");

  __shared__ float hl[4][520];
  __shared__ int   tokD[TD][4];
  __shared__ int   lensh[4];
  __shared__ float av8v[8];
  __shared__ float hpv[4][8];
  __shared__ float elds[4][128];
  __shared__ float wlds[4][128];
  __shared__ float mxs[4], invs[4];
  __shared__ float gvc[4][48];
  __shared__ float lds_pd[2][4][4][52];

  for (int i = tid; i < TD * 4; i += 512)
    tokD[i >> 2][i & 3] = dec_in[(B4 + (i & 3)) * TD + (i >> 2)];
  if (tid < 8) av8v[tid] = attn_v[tid];
  if (tid < 4) lensh[tid] = lens[B4 + tid];

  if (tid < 64) {
    int bb = tid >> 4, col = tid & 15;
    stg1(&hd[(size_t)(B4 + bb) * HH + cg * 16 + col], 0.0f);
  }

  {
    const int idx = cg * 512 + tid;
    if (idx < 4 * TE * 8) {
      int a = idx & 7, t = (idx >> 3) & 127, bb = idx >> 10;
      int b = B4 + bb;
      float acc = attn_b[a];
      const float* er = &eo[((size_t)b * TE + t) * CTXD];
      for (int d = 0; d < CTXD; d += 4) {
        float4 ev = *(const float4*)&er[d];
        acc = fmaf(ev.x, attn_W[(d + 0) * 8 + a], acc);
        acc = fmaf(ev.y, attn_W[(d + 1) * 8 + a], acc);
        acc = fmaf(ev.z, attn_W[(d + 2) * 8 + a], acc);
        acc = fmaf(ev.w, attn_W[(d + 3) * 8 + a], acc);
      }
      stg1(&ep[((size_t)b * TE + t) * 8 + a], acc);
    }
  }

  const int lane = tid & 63, w = tid >> 6;
  const int ks = w & 3, rh = w >> 2;
  const int rq = lane >> 4, kl = lane & 15;
  float4 Wreg[6][3];
  #pragma unroll
  for (int ri = 0; ri < 6; ++ri) {
    int rr = rh * 24 + rq * 6 + ri;
    int row = (rr >> 4) * HH + cg * 16 + (rr & 15);
    #pragma unroll
    for (int p = 0; p < 3; ++p) {
      int c = ks * 3 + p;
      Wreg[ri][p] = (c < 4)
        ? *(const float4*)(gWih + (size_t)row * (EMB + CTXD) + c * 64 + kl * 4)
        : *(const float4*)(gWhh + (size_t)row * HH + (c - 4) * 64 + kl * 4);
    }
  }

  const int ub = tid >> 4, ucol = tid & 15;
  const int uj = cg * 16 + ucol;
  float bRc = 0, bZc = 0, bNi = 0, bNh = 0;
  if (tid < 64) {
    bRc = gbih[uj] + gbhh[uj];
    bZc = gbih[HH + uj] + gbhh[HH + uj];
    bNi = gbih[2 * HH + uj];
    bNh = gbhh[2 * HH + uj];
  }

  int tgt = 32;
  gbarG(bar, cg, tgt); tgt += 32;

  for (int s = 0; s < TD; ++s) {
    {
      int bb = tid >> 7, c4 = (tid & 127) * 4;
      *(float4*)&hl[bb][c4] =
        *(const float4*)&hd[((size_t)s * NB + B4 + bb) * HH + c4];
    }
    __syncthreads();
    {
      const int bb = w >> 1;
      const float4* h4 = (const float4*)&hl[bb][0];
      float4 ha = h4[lane * 2], hb = h4[lane * 2 + 1];
      #pragma unroll
      for (int i = 0; i < 4; ++i) {
        const int a = (w & 1) * 4 + i;
        const float* wa = attn_W + (size_t)(CTXD + lane * 8) * 8 + a;
        float acc = 0.0f;
        acc = fmaf(ha.x, wa[0],  acc); acc = fmaf(ha.y, wa[8],  acc);
        acc = fmaf(ha.z, wa[16], acc); acc = fmaf(ha.w, wa[24], acc);
        acc = fmaf(hb.x, wa[32], acc); acc = fmaf(hb.y, wa[40], acc);
        acc = fmaf(hb.z, wa[48], acc); acc = fmaf(hb.w, wa[56], acc);
        acc += __shfl_xor(acc, 1);  acc += __shfl_xor(acc, 2);
        acc += __shfl_xor(acc, 4);  acc += __shfl_xor(acc, 8);
        acc += __shfl_xor(acc, 16); acc += __shfl_xor(acc, 32);
        if (lane == 0) hpv[bb][a] = acc;
      }
    }
    __syncthreads();
    {
      const int bb = tid >> 7, t = tid & 127;
      const int b = B4 + bb;
      float evv = -1e9f;
      if (t < lensh[bb]) {
        const float* e8 = &ep[((size_t)b * TE + t) * 8];
        float4 ea = *(const float4*)e8, eb2 = *(const float4*)(e8 + 4);
        evv  = tanhf(ea.x + hpv[bb][0]) * av8v[0];
        evv += tanhf(ea.y + hpv[bb][1]) * av8v[1];
        evv += tanhf(ea.z + hpv[bb][2]) * av8v[2];
        evv += tanhf(ea.w + hpv[bb][3]) * av8v[3];
        evv += tanhf(eb2.x + hpv[bb][4]) * av8v[4];
        evv += tanhf(eb2.y + hpv[bb][5]) * av8v[5];
        evv += tanhf(eb2.z + hpv[bb][6]) * av8v[6];
        evv += tanhf(eb2.w + hpv[bb][7]) * av8v[7];
      }
      elds[bb][t] = evv;
    }
    __syncthreads();
    if (tid < 256) {
      const int bb = tid >> 6, i = tid & 63;
      float m = fmaxf(elds[bb][i], elds[bb][i + 64]);
      m = fmaxf(m, __shfl_xor(m, 1));  m = fmaxf(m, __shfl_xor(m, 2));
      m = fmaxf(m, __shfl_xor(m, 4));  m = fmaxf(m, __shfl_xor(m, 8));
      m = fmaxf(m, __shfl_xor(m, 16)); m = fmaxf(m, __shfl_xor(m, 32));
      if (i == 0) mxs[bb] = m;
    }
    __syncthreads();
    {
      const int bb = tid >> 7, t = tid & 127;
      wlds[bb][t] = expf(elds[bb][t] - mxs[bb]);
    }
    __syncthreads();
    if (tid < 256) {
      const int bb = tid >> 6, i = tid & 63;
      float sm = wlds[bb][i] + wlds[bb][i + 64];
      sm += __shfl_xor(sm, 1);  sm += __shfl_xor(sm, 2);
      sm += __shfl_xor(sm, 4);  sm += __shfl_xor(sm, 8);
      sm += __shfl_xor(sm, 16); sm += __shfl_xor(sm, 32);
      if (i == 0) invs[bb] = 1.0f / sm;
    }
    {
      #pragma unroll
      for (int bb = 0; bb < 4; ++bb) {
        const float4* xr = (const float4*)(emb_tgt + (size_t)tokD[s][bb] * EMB);
        float4 u[3];
        #pragma unroll
        for (int p = 0; p < 3; ++p) {
          int c = ks * 3 + p;
          u[p] = (c < 4) ? xr[c * 16 + kl]
                         : *(const float4*)&hl[bb][(c - 4) * 64 + kl * 4];
        }
        float sI[6], sH[6];
        #pragma unroll
        for (int ri = 0; ri < 6; ++ri) {
          float4 aI = {0,0,0,0}, aH = {0,0,0,0};
          #pragma unroll
          for (int p = 0; p < 3; ++p) {
            int c = ks * 3 + p;
            if (c < 4) fma4(aI, Wreg[ri][p], u[p]);
            else       fma4(aH, Wreg[ri][p], u[p]);
          }
          sI[ri] = hsum4(aI); sH[ri] = hsum4(aH);
        }
        #pragma unroll
        for (int ri = 0; ri < 6; ++ri) {
          sI[ri] += __shfl_xor(sI[ri], 1); sH[ri] += __shfl_xor(sH[ri], 1);
          sI[ri] += __shfl_xor(sI[ri], 2); sH[ri] += __shfl_xor(sH[ri], 2);
          sI[ri] += __shfl_xor(sI[ri], 4); sH[ri] += __shfl_xor(sH[ri], 4);
          sI[ri] += __shfl_xor(sI[ri], 8); sH[ri] += __shfl_xor(sH[ri], 8);
        }
        if (kl == 0) {
          int r0 = rh * 24 + rq * 6;
          #pragma unroll
          for (int ri = 0; ri < 6; ++ri) {
            lds_pd[0][bb][ks][r0 + ri] = sI[ri];
            lds_pd[1][bb][ks][r0 + ri] = sH[ri];
          }
        }
      }
    }
    __syncthreads();
    if (tid < 384) {
      const int bb = tid / 96, idx = tid % 96;
      const int rr = idx >> 1, th = idx & 1;
      const int n = (rr >> 4) * HH + cg * 16 + (rr & 15);
      const unsigned short* vp = veoH + ((size_t)(B4 + bb) * NR + n) * TE + th * 64;
      const float* wl = &wlds[bb][th * 64];
      float acc = 0.0f;
      #pragma unroll
      for (int q = 0; q < 8; ++q) {
        uint4 pk = *(const uint4*)&vp[q * 8];
        unsigned int uu[4] = {pk.x, pk.y, pk.z, pk.w};
        #pragma unroll
        for (int h2 = 0; h2 < 4; ++h2) {
          acc = fmaf(wl[q * 8 + h2 * 2 + 0],
                     __uint_as_float((uu[h2] & 0xFFFFu) << 16), acc);
          acc = fmaf(wl[q * 8 + h2 * 2 + 1],
                     __uint_as_float((uu[h2] >> 16) << 16), acc);
        }
      }
      acc += __shfl_xor(acc, 1);
      if (th == 0) gvc[bb][rr] = acc * invs[bb];
    }
    __syncthreads();
    if (tid < 64) {
      float giR = gvc[ub][ucol], ghR = 0;
      float giZ = gvc[ub][16 + ucol], ghZ = 0;
      float giN = gvc[ub][32 + ucol], ghN = 0;
      #pragma unroll
      for (int k2 = 0; k2 < 4; ++k2) {
        giR += lds_pd[0][ub][k2][ucol];      ghR += lds_pd[1][ub][k2][ucol];
        giZ += lds_pd[0][ub][k2][16 + ucol]; ghZ += lds_pd[1][ub][k2][16 + ucol];
        giN += lds_pd[0][ub][k2][32 + ucol]; ghN += lds_pd[1][ub][k2][32 + ucol];
      }
      float r = sigf(giR + ghR + bRc);
      float z = sigf(giZ + ghZ + bZc);
      float n = tanhf(giN + bNi + r * (ghN + bNh));
      float hnew = (1.0f - z) * n + z * hl[ub][uj];
      stg1(&hd[((size_t)(s + 1) * NB + B4 + ub) * HH + uj], hnew);
    }
    gbarG(bar, cg, tgt); tgt += 32;
  }
}

// ------- conv: split hdec into exact bf16 hi+lo, output-row (m) order -------
__global__ void __launch_bounds__(256)
conv_kernel(const float* __restrict__ hd,
            unsigned short* __restrict__ Abh, unsigned short* __restrict__ Abl)
{
  asm volatile("buffer_inv sc1" ::: "memory");
  const int idx = blockIdx.x * 256 + threadIdx.x;   // 0..65535
  const int m = idx >> 6;
  const int k8 = (idx & 63) * 8;
  const float* src = hd + ((size_t)((m & 31) + 1) * NB + (m >> 5)) * HH + k8;
  float4 a0 = *(const float4*)src;
  float4 a1 = *(const float4*)(src + 4);
  float f[8] = {a0.x, a0.y, a0.z, a0.w, a1.x, a1.y, a1.z, a1.w};
  unsigned short hi[8], lo[8];
  #pragma unroll
  for (int i = 0; i < 8; ++i) {
    unsigned short h = to_bf16(f[i]);
    float fh = __uint_as_float(((unsigned int)h) << 16);
    hi[i] = h;
    lo[i] = to_bf16(f[i] - fh);
  }
  *(uint4*)&Abh[(size_t)m * HH + k8] = *(uint4*)hi;
  *(uint4*)&Abl[(size_t)m * HH + k8] = *(uint4*)lo;
}

// -------- Classifier (R14 verbatim): bf16 MFMA, 2-term compensation --------
__global__ void __launch_bounds__(256)
clf_kernel(const unsigned short* __restrict__ Abh, const unsigned short* __restrict__ Abl,
           const float* __restrict__ W, const float* __restrict__ bias,
           float* __restrict__ out)
{
  asm volatile("buffer_inv sc1" ::: "memory");
  __shared__ __align__(16) unsigned short Ah[256][40];
  __shared__ __align__(16) unsigned short Al[256][40];
  __shared__ __align__(16) unsigned short Wh[128][40];
  const int tid = threadIdx.x;
  const int wv = tid >> 6, l = tid & 63;
  const int lr = l & 15, lkq = l >> 4;
  const int n0 = blockIdx.x * 128, m0 = blockIdx.y * 256;
  f32x4 acc[2][16] = {};

  for (int kc = 0; kc < HH; kc += 32) {
    __syncthreads();
    {
      const unsigned short* sh = Abh + (size_t)(m0 + tid) * HH + kc;
      const unsigned short* sl = Abl + (size_t)(m0 + tid) * HH + kc;
      uint4 h0 = *(const uint4*)(sh);      uint4 h1 = *(const uint4*)(sh + 8);
      uint4 h2 = *(const uint4*)(sh + 16); uint4 h3 = *(const uint4*)(sh + 24);
      uint4 l0 = *(const uint4*)(sl);      uint4 l1 = *(const uint4*)(sl + 8);
      uint4 l2 = *(const uint4*)(sl + 16); uint4 l3 = *(const uint4*)(sl + 24);
      *(uint4*)&Ah[tid][0]  = h0; *(uint4*)&Ah[tid][8]  = h1;
      *(uint4*)&Ah[tid][16] = h2; *(uint4*)&Ah[tid][24] = h3;
      *(uint4*)&Al[tid][0]  = l0; *(uint4*)&Al[tid][8]  = l1;
      *(uint4*)&Al[tid][16] = l2; *(uint4*)&Al[tid][24] = l3;
      const int wr = tid >> 1, hf = tid & 1;
      const float* wsrc = W + (size_t)(n0 + wr) * HH + kc + hf * 16;
      unsigned int o[8];
      #pragma unroll
      for (int i = 0; i < 16; i += 4) {
        float4 v = *(const float4*)&wsrc[i];
        o[(i >> 1) + 0] = (unsigned int)to_bf16(v.x) | ((unsigned int)to_bf16(v.y) << 16);
        o[(i >> 1) + 1] = (unsigned int)to_bf16(v.z) | ((unsigned int)to_bf16(v.w) << 16);
      }
      *(uint4*)&Wh[wr][hf * 16]     = *(uint4*)&o[0];
      *(uint4*)&Wh[wr][hf * 16 + 8] = *(uint4*)&o[4];
    }
    __syncthreads();
    bf16x8 bfr[2];
    bfr[0] = *(const bf16x8*)&Wh[wv * 32 + lr][lkq * 8];
    bfr[1] = *(const bf16x8*)&Wh[wv * 32 + 16 + lr][lkq * 8];
    #pragma unroll
    for (int mf = 0; mf < 16; ++mf) {
      bf16x8 ah = *(const bf16x8*)&Ah[mf * 16 + lr][lkq * 8];
      bf16x8 al = *(const bf16x8*)&Al[mf * 16 + lr][lkq * 8];
      #pragma unroll
      for (int nf = 0; nf < 2; ++nf) {
        acc[nf][mf] = __builtin_amdgcn_mfma_f32_16x16x32_bf16(ah, bfr[nf], acc[nf][mf], 0, 0, 0);
        acc[nf][mf] = __builtin_amdgcn_mfma_f32_16x16x32_bf16(al, bfr[nf], acc[nf][mf], 0, 0, 0);
      }
    }
  }
  #pragma unroll
  for (int nf = 0; nf < 2; ++nf) {
    const int n = n0 + wv * 32 + nf * 16 + lr;
    const float bn = bias[n];
    #pragma unroll
    for (int mf = 0; mf < 16; ++mf) {
      #pragma unroll
      for (int r = 0; r < 4; ++r) {
        int m = m0 + mf * 16 + lkq * 4 + r;
        out[(size_t)m * VOC + n] = fmaxf(acc[nf][mf][r] + bn, 0.0f);
      }
    }
  }
}

extern "C" void kernel_launch(void* const* d_in, const int* in_sizes, int n_in,
                              void* d_out, int out_size, void* d_ws, size_t ws_size,
                              hipStream_t stream)
{
  if (ws_size < (size_t)WSEND * 4) return;  // visible-failure guard

  const int* enc_in  = (const int*)d_in[0];
  const int* enc_len = (const int*)d_in[1];
  const int* dec_in  = (const int*)d_in[2];
  const float* emb_src = (const float*)d_in[4];
  const float* emb_tgt = (const float*)d_in[5];
  const float* Wih_f = (const float*)d_in[6];
  const float* Whh_f = (const float*)d_in[7];
  const float* bih_f = (const float*)d_in[8];
  const float* bhh_f = (const float*)d_in[9];
  const float* Wih_b = (const float*)d_in[10];
  const float* Whh_b = (const float*)d_in[11];
  const float* bih_b = (const float*)d_in[12];
  const float* bhh_b = (const float*)d_in[13];
  const float* gWih  = (const float*)d_in[14];
  const float* gWhh  = (const float*)d_in[15];
  const float* gbih  = (const float*)d_in[16];
  const float* gbhh  = (const float*)d_in[17];
  const float* attn_W = (const float*)d_in[18];
  const float* attn_b = (const float*)d_in[19];
  const float* attn_v = (const float*)d_in[20];
  const float* clf_W = (const float*)d_in[21];
  const float* clf_b = (const float*)d_in[22];
  float* ws  = (float*)d_ws;
  float* out = (float*)d_out;

  unsigned short* Abh = (unsigned short*)(ws + OHS);          // dead harr region
  unsigned short* Abl = Abh + (size_t)NB * TD * HH;

  hipMemsetAsync(d_ws, 0, 20480, stream);  // scan flags (16KB) + dec bars (4KB)
  scan_kernel<<<256, 512, 0, stream>>>(enc_in, enc_len, emb_src,
      Wih_f, Whh_f, bih_f, bhh_f, Wih_b, Whh_b, bih_b, bhh_b, ws);
  veo_kernel<<<dim3(NR / 128, (NB * TE) / 128), 256, 0, stream>>>(
      ws + OEO, gWih, (unsigned short*)(ws + OVEO));
  dec_kernel<<<256, 512, 0, stream>>>(dec_in, enc_len, emb_tgt,
      gWih, gWhh, gbih, gbhh, attn_W, attn_b, attn_v, ws);
  conv_kernel<<<256, 256, 0, stream>>>(ws + OHD, Abh, Abl);
  dim3 cg(VOC / 128, (NB * TD) / 256);
  clf_kernel<<<cg, 256, 0, stream>>>(Abh, Abl, clf_W, clf_b, out);
}